// Round 2
// baseline (402.681 us; speedup 1.0000x reference)
//
#include <hip/hip_runtime.h>

// Workspace layout (floats). Requires ws_size >= ~118 MB.
#define H1_OFF   0u            // h1: 4096*16*16*16 = 16777216 floats
#define H2_OFF   16777216u     // h2: 4096*32*8*8   =  8388608 floats
#define H3_OFF   25165824u     // h3: 4096*64*4*4   =  4194304 floats
#define W2T_OFF  29360128u     // w2 transposed [ic][ky][kx][oc] : 16*9*32  = 4608
#define W3T_OFF  29364736u     // w3 transposed [ic][ky][kx][oc] : 32*9*64  = 18432

// ---------------------------------------------------------------- transpose
__global__ __launch_bounds__(256) void transpose_weights(
    const float* __restrict__ w2, const float* __restrict__ w3,
    float* __restrict__ ws) {
  int i = blockIdx.x * 256 + threadIdx.x;
  if (i < 4608) {                       // w2 [32][16*9] -> w2t [16*9][32]
    int oc = i / 144, r = i % 144;
    ws[W2T_OFF + r * 32 + oc] = w2[i];
  }
  int j = i - 4608;
  if (j >= 0 && j < 18432) {            // w3 [64][32*9] -> w3t [32*9][64]
    int oc = j / 288, r = j % 288;
    ws[W3T_OFF + r * 64 + oc] = w3[j];
  }
}

// ------------------------------------------------------------------- conv1
// x[4096,3,32,32] -> relu+pool -> h1[4096,16,16,16]. 1 image per block.
// LDS row stride 36 floats (144B, 16B-aligned rows -> b128 window reads).
__global__ __launch_bounds__(256) void conv1_kernel(
    const float* __restrict__ x, const float* __restrict__ w1,
    const float* __restrict__ b1, float* __restrict__ h1) {
  __shared__ __align__(16) float s_in[3 * 34 * 36];  // 14.7 KB
  __shared__ __align__(16) float s_w[27 * 16];       // [ic*9+t][oc]
  const int tid = threadIdx.x;
  const int b = blockIdx.x;

  for (int i = tid; i < 3 * 34 * 36; i += 256) s_in[i] = 0.f;
  __syncthreads();
  for (int i = tid; i < 3 * 1024; i += 256) {
    int c = i >> 10, rem = i & 1023, y = rem >> 5, xx = rem & 31;
    s_in[c * 1224 + (y + 1) * 36 + (xx + 1)] = x[b * 3072 + i];
  }
  for (int i = tid; i < 432; i += 256) {
    int oc = i / 27, r = i % 27;
    s_w[r * 16 + oc] = w1[i];
  }
  __syncthreads();

  const int ocg = tid & 3;        // 4 groups x 4 oc = 16 oc
  const int tile = tid >> 2;      // 64 tiles (8x8 of 4x4-conv regions)
  const int ty = tile >> 3, tx = tile & 7;
  const int Y = 4 * ty, X = 4 * tx;

  float acc[4][16];
  #pragma unroll
  for (int i = 0; i < 4; ++i)
    #pragma unroll
    for (int j = 0; j < 16; ++j) acc[i][j] = 0.f;

  #pragma unroll
  for (int ic = 0; ic < 3; ++ic) {
    float win[6][6];
    const int base = ic * 1224 + Y * 36 + X;
    #pragma unroll
    for (int r = 0; r < 6; ++r) {
      const float4 a4 = *(const float4*)&s_in[base + r * 36];
      const float2 a2 = *(const float2*)&s_in[base + r * 36 + 4];
      win[r][0] = a4.x; win[r][1] = a4.y; win[r][2] = a4.z; win[r][3] = a4.w;
      win[r][4] = a2.x; win[r][5] = a2.y;
    }
    #pragma unroll
    for (int t = 0; t < 9; ++t) {
      const int ky = t / 3, kx = t % 3;
      const float4 w = *(const float4*)&s_w[(ic * 9 + t) * 16 + ocg * 4];
      #pragma unroll
      for (int r = 0; r < 4; ++r)
        #pragma unroll
        for (int c = 0; c < 4; ++c) {
          const float v = win[r + ky][c + kx];
          acc[0][r * 4 + c] = fmaf(v, w.x, acc[0][r * 4 + c]);
          acc[1][r * 4 + c] = fmaf(v, w.y, acc[1][r * 4 + c]);
          acc[2][r * 4 + c] = fmaf(v, w.z, acc[2][r * 4 + c]);
          acc[3][r * 4 + c] = fmaf(v, w.w, acc[3][r * 4 + c]);
        }
    }
  }
  #pragma unroll
  for (int oci = 0; oci < 4; ++oci) {
    const int oc = ocg * 4 + oci;
    const float bias = b1[oc];
    #pragma unroll
    for (int pyi = 0; pyi < 2; ++pyi)
      #pragma unroll
      for (int pxi = 0; pxi < 2; ++pxi) {
        const int r0 = 2 * pyi, c0 = 2 * pxi;
        float m = fmaxf(fmaxf(acc[oci][r0 * 4 + c0], acc[oci][r0 * 4 + c0 + 1]),
                        fmaxf(acc[oci][(r0 + 1) * 4 + c0], acc[oci][(r0 + 1) * 4 + c0 + 1]));
        const int py = 2 * ty + pyi, px = 2 * tx + pxi;
        h1[((b * 16 + oc) << 8) + py * 16 + px] = fmaxf(m + bias, 0.f);
      }
  }
}

// ------------------------------------------------------------------- conv2
// h1[4096,16,16,16] -> relu+pool -> h2[4096,32,8,8]. 2 images per block.
// LDS row stride 20 floats (80B, 16B-aligned rows -> b128+b64 window reads).
__global__ __launch_bounds__(256, 3) void conv2_kernel(
    const float* __restrict__ h1, const float* __restrict__ w2t,
    const float* __restrict__ b2, float* __restrict__ h2) {
  __shared__ __align__(16) float s_in[2 * 16 * 18 * 20];  // 46.1 KB -> 3 blocks/CU
  const int tid = threadIdx.x;
  const int b0 = blockIdx.x * 2;

  for (int i = tid; i < 11520; i += 256) s_in[i] = 0.f;
  __syncthreads();
  for (int i = tid; i < 8192; i += 256) {
    int img = i >> 12, rem = i & 4095;
    int c = rem >> 8, y = (rem >> 4) & 15, xx = rem & 15;
    s_in[img * 5760 + c * 360 + (y + 1) * 20 + (xx + 1)] = h1[(b0 + img) * 4096 + rem];
  }
  __syncthreads();

  const int ocg = tid & 7;            // 8 groups x 4 oc = 32
  const int tile = (tid >> 3) & 15;   // 16 tiles
  const int img = tid >> 7;           // 2 images
  const int ty = tile >> 2, tx = tile & 3;
  const int Y = 4 * ty, X = 4 * tx;
  const float* __restrict__ wbase = w2t + ocg * 4;

  float acc[4][16];
  #pragma unroll
  for (int i = 0; i < 4; ++i)
    #pragma unroll
    for (int j = 0; j < 16; ++j) acc[i][j] = 0.f;

  const int ibase0 = img * 5760 + Y * 20 + X;
  #pragma unroll 2
  for (int ic = 0; ic < 16; ++ic) {
    float win[6][6];
    const int base = ibase0 + ic * 360;
    #pragma unroll
    for (int r = 0; r < 6; ++r) {
      const float4 a4 = *(const float4*)&s_in[base + r * 20];
      const float2 a2 = *(const float2*)&s_in[base + r * 20 + 4];
      win[r][0] = a4.x; win[r][1] = a4.y; win[r][2] = a4.z; win[r][3] = a4.w;
      win[r][4] = a2.x; win[r][5] = a2.y;
    }
    const float* __restrict__ wc = wbase + ic * 288;  // 9 taps via imm offsets
    #pragma unroll
    for (int t = 0; t < 9; ++t) {
      const float4 w = *(const float4*)&wc[t * 32];
      const int ky = t / 3, kx = t % 3;
      #pragma unroll
      for (int r = 0; r < 4; ++r)
        #pragma unroll
        for (int c = 0; c < 4; ++c) {
          const float v = win[r + ky][c + kx];
          acc[0][r * 4 + c] = fmaf(v, w.x, acc[0][r * 4 + c]);
          acc[1][r * 4 + c] = fmaf(v, w.y, acc[1][r * 4 + c]);
          acc[2][r * 4 + c] = fmaf(v, w.z, acc[2][r * 4 + c]);
          acc[3][r * 4 + c] = fmaf(v, w.w, acc[3][r * 4 + c]);
        }
    }
  }
  #pragma unroll
  for (int oci = 0; oci < 4; ++oci) {
    const int oc = ocg * 4 + oci;
    const float bias = b2[oc];
    #pragma unroll
    for (int pyi = 0; pyi < 2; ++pyi)
      #pragma unroll
      for (int pxi = 0; pxi < 2; ++pxi) {
        const int r0 = 2 * pyi, c0 = 2 * pxi;
        float m = fmaxf(fmaxf(acc[oci][r0 * 4 + c0], acc[oci][r0 * 4 + c0 + 1]),
                        fmaxf(acc[oci][(r0 + 1) * 4 + c0], acc[oci][(r0 + 1) * 4 + c0 + 1]));
        const int py = 2 * ty + pyi, px = 2 * tx + pxi;
        h2[((b0 + img) * 32 + oc) * 64 + py * 8 + px] = fmaxf(m + bias, 0.f);
      }
  }
}

// ------------------------------------------------------------------- conv3
// h2[4096,32,8,8] -> relu+pool -> h3[4096,64,4,4]. 4 images per block.
// Stride kept at 10 (padding to 12 would drop a block/CU); rows read as 3xb64.
__global__ __launch_bounds__(256, 3) void conv3_kernel(
    const float* __restrict__ h2, const float* __restrict__ w3t,
    const float* __restrict__ b3, float* __restrict__ h3) {
  __shared__ __align__(16) float s_in[4 * 32 * 10 * 10];  // 51.2 KB -> 3 blocks/CU
  const int tid = threadIdx.x;
  const int b0 = blockIdx.x * 4;

  for (int i = tid; i < 12800; i += 256) s_in[i] = 0.f;
  __syncthreads();
  for (int i = tid; i < 8192; i += 256) {
    int img = i >> 11, rem = i & 2047;
    int c = rem >> 6, y = (rem >> 3) & 7, xx = rem & 7;
    s_in[img * 3200 + c * 100 + (y + 1) * 10 + (xx + 1)] = h2[(b0 + img) * 2048 + rem];
  }
  __syncthreads();

  const int ocg = tid & 15;           // 16 groups x 4 oc = 64
  const int tile = (tid >> 4) & 3;    // 4 tiles
  const int img = tid >> 6;           // 4 images (one wave per image)
  const int ty = tile >> 1, tx = tile & 1;
  const int Y = 4 * ty, X = 4 * tx;
  const float* __restrict__ wbase = w3t + ocg * 4;

  float acc[4][16];
  #pragma unroll
  for (int i = 0; i < 4; ++i)
    #pragma unroll
    for (int j = 0; j < 16; ++j) acc[i][j] = 0.f;

  const int ibase0 = img * 3200 + Y * 10 + X;
  #pragma unroll 2
  for (int ic = 0; ic < 32; ++ic) {
    float win[6][6];
    const int base = ibase0 + ic * 100;
    #pragma unroll
    for (int r = 0; r < 6; ++r) {
      const float2 a0 = *(const float2*)&s_in[base + r * 10];
      const float2 a1 = *(const float2*)&s_in[base + r * 10 + 2];
      const float2 a2 = *(const float2*)&s_in[base + r * 10 + 4];
      win[r][0] = a0.x; win[r][1] = a0.y; win[r][2] = a1.x;
      win[r][3] = a1.y; win[r][4] = a2.x; win[r][5] = a2.y;
    }
    const float* __restrict__ wc = wbase + ic * 576;  // 9 taps via imm offsets
    #pragma unroll
    for (int t = 0; t < 9; ++t) {
      const float4 w = *(const float4*)&wc[t * 64];
      const int ky = t / 3, kx = t % 3;
      #pragma unroll
      for (int r = 0; r < 4; ++r)
        #pragma unroll
        for (int c = 0; c < 4; ++c) {
          const float v = win[r + ky][c + kx];
          acc[0][r * 4 + c] = fmaf(v, w.x, acc[0][r * 4 + c]);
          acc[1][r * 4 + c] = fmaf(v, w.y, acc[1][r * 4 + c]);
          acc[2][r * 4 + c] = fmaf(v, w.z, acc[2][r * 4 + c]);
          acc[3][r * 4 + c] = fmaf(v, w.w, acc[3][r * 4 + c]);
        }
    }
  }
  #pragma unroll
  for (int oci = 0; oci < 4; ++oci) {
    const int oc = ocg * 4 + oci;
    const float bias = b3[oc];
    #pragma unroll
    for (int pyi = 0; pyi < 2; ++pyi)
      #pragma unroll
      for (int pxi = 0; pxi < 2; ++pxi) {
        const int r0 = 2 * pyi, c0 = 2 * pxi;
        float m = fmaxf(fmaxf(acc[oci][r0 * 4 + c0], acc[oci][r0 * 4 + c0 + 1]),
                        fmaxf(acc[oci][(r0 + 1) * 4 + c0], acc[oci][(r0 + 1) * 4 + c0 + 1]));
        const int py = 2 * ty + pyi, px = 2 * tx + pxi;
        h3[((b0 + img) * 64 + oc) * 16 + py * 4 + px] = fmaxf(m + bias, 0.f);
      }
  }
}

// ---------------------------------------------------------------------- fc
// h3[4096,1024] @ fc_w[10,1024]^T + fc_b -> out[4096,10]. One wave per image.
__global__ __launch_bounds__(256) void fc_kernel(
    const float* __restrict__ h3, const float* __restrict__ fw,
    const float* __restrict__ fb, float* __restrict__ out) {
  const int tid = threadIdx.x;
  const int lane = tid & 63;
  const int b = blockIdx.x * 4 + (tid >> 6);
  float hv[16];
  #pragma unroll
  for (int i = 0; i < 16; ++i) hv[i] = h3[b * 1024 + i * 64 + lane];
  #pragma unroll
  for (int j = 0; j < 10; ++j) {
    float dot = 0.f;
    #pragma unroll
    for (int i = 0; i < 16; ++i)
      dot = fmaf(hv[i], fw[j * 1024 + i * 64 + lane], dot);
    #pragma unroll
    for (int s = 32; s > 0; s >>= 1) dot += __shfl_xor(dot, s, 64);
    if (lane == 0) out[b * 10 + j] = dot + fb[j];
  }
}

// -------------------------------------------------------------------- launch
extern "C" void kernel_launch(void* const* d_in, const int* in_sizes, int n_in,
                              void* d_out, int out_size, void* d_ws, size_t ws_size,
                              hipStream_t stream) {
  const float* x   = (const float*)d_in[0];
  const float* w1  = (const float*)d_in[1];
  const float* b1  = (const float*)d_in[2];
  const float* w2  = (const float*)d_in[3];
  const float* b2  = (const float*)d_in[4];
  const float* w3  = (const float*)d_in[5];
  const float* b3  = (const float*)d_in[6];
  const float* fcw = (const float*)d_in[7];
  const float* fcb = (const float*)d_in[8];
  float* ws  = (float*)d_ws;
  float* out = (float*)d_out;

  hipLaunchKernelGGL(transpose_weights, dim3(90), dim3(256), 0, stream, w2, w3, ws);
  hipLaunchKernelGGL(conv1_kernel, dim3(4096), dim3(256), 0, stream,
                     x, w1, b1, ws + H1_OFF);
  hipLaunchKernelGGL(conv2_kernel, dim3(2048), dim3(256), 0, stream,
                     ws + H1_OFF, ws + W2T_OFF, b2, ws + H2_OFF);
  hipLaunchKernelGGL(conv3_kernel, dim3(1024), dim3(256), 0, stream,
                     ws + H2_OFF, ws + W3T_OFF, b3, ws + H3_OFF);
  hipLaunchKernelGGL(fc_kernel, dim3(1024), dim3(256), 0, stream,
                     ws + H3_OFF, fcw, fcb, out);
}

// Round 3
// 350.275 us; speedup vs baseline: 1.1496x; 1.1496x over previous
//
#include <hip/hip_runtime.h>

typedef float f32x2 __attribute__((ext_vector_type(2)));
typedef float f32x4 __attribute__((ext_vector_type(4)));

// Packed fp32 FMA (VOP3P v_pk_fma_f32, gfx90a+). acc.{lo,hi} += v * w.{lo,hi}
// where v is selected from ONE half of the aligned pair vp via op_sel.
__device__ __forceinline__ void pk_fma_lo(f32x2 &acc, f32x2 vp, f32x2 w) {
  // v = vp.lo for both halves
  asm("v_pk_fma_f32 %0, %1, %2, %0 op_sel_hi:[0,1,1]"
      : "+v"(acc) : "v"(vp), "v"(w));
}
__device__ __forceinline__ void pk_fma_hi(f32x2 &acc, f32x2 vp, f32x2 w) {
  // v = vp.hi for both halves
  asm("v_pk_fma_f32 %0, %1, %2, %0 op_sel:[1,0,0] op_sel_hi:[1,1,1]"
      : "+v"(acc) : "v"(vp), "v"(w));
}

// Workspace layout (floats). Requires ws_size >= ~118 MB.
#define H1_OFF   0u            // h1: 4096*16*16*16 = 16777216 floats
#define H2_OFF   16777216u     // h2: 4096*32*8*8   =  8388608 floats
#define H3_OFF   25165824u     // h3: 4096*64*4*4   =  4194304 floats
#define W2T_OFF  29360128u     // w2t [ic][ky][kx][oc] : 16*9*32 = 4608
#define W3T_OFF  29364736u     // w3t [ic][ky][kx][oc] : 32*9*64 = 18432

// ---------------------------------------------------------------- transpose
__global__ __launch_bounds__(256) void transpose_weights(
    const float* __restrict__ w2, const float* __restrict__ w3,
    float* __restrict__ ws) {
  int i = blockIdx.x * 256 + threadIdx.x;
  if (i < 4608) {
    int oc = i / 144, r = i % 144;
    ws[W2T_OFF + r * 32 + oc] = w2[i];
  }
  int j = i - 4608;
  if (j >= 0 && j < 18432) {
    int oc = j / 288, r = j % 288;
    ws[W3T_OFF + r * 64 + oc] = w3[j];
  }
}

// ------------------------------------------------------------------- conv1
// x[4096,3,32,32] -> relu+pool -> h1[4096,16,16,16]. 1 image/block. stride 34.
__global__ __launch_bounds__(256) void conv1_kernel(
    const float* __restrict__ x, const float* __restrict__ w1,
    const float* __restrict__ b1, float* __restrict__ h1) {
  __shared__ __align__(16) float s_in[3 * 34 * 34];
  __shared__ __align__(16) float s_w[27 * 16];
  const int tid = threadIdx.x;
  const int b = blockIdx.x;

  for (int i = tid; i < 3 * 34 * 34; i += 256) s_in[i] = 0.f;
  __syncthreads();
  for (int i = tid; i < 3 * 1024; i += 256) {
    int c = i >> 10, rem = i & 1023, y = rem >> 5, xx = rem & 31;
    s_in[c * 1156 + (y + 1) * 34 + (xx + 1)] = x[b * 3072 + i];
  }
  for (int i = tid; i < 432; i += 256) {
    int oc = i / 27, r = i % 27;
    s_w[r * 16 + oc] = w1[i];
  }
  __syncthreads();

  const int ocg = tid & 3;
  const int tile = tid >> 2;
  const int ty = tile >> 3, tx = tile & 7;
  const int Y = 4 * ty, X = 4 * tx;

  f32x2 acc01[16], acc23[16];
  #pragma unroll
  for (int i = 0; i < 16; ++i) { acc01[i] = (f32x2)(0.f); acc23[i] = (f32x2)(0.f); }

  #pragma unroll
  for (int ic = 0; ic < 3; ++ic) {
    f32x2 wp[6][3];
    const int base = ic * 1156 + Y * 34 + X;
    #pragma unroll
    for (int r = 0; r < 6; ++r)
      #pragma unroll
      for (int j = 0; j < 3; ++j) {
        wp[r][j].x = s_in[base + r * 34 + 2 * j];
        wp[r][j].y = s_in[base + r * 34 + 2 * j + 1];
      }
    #pragma unroll
    for (int t = 0; t < 9; ++t) {
      const int ky = t / 3, kx = t % 3;
      const f32x4 w4 = *(const f32x4*)&s_w[(ic * 9 + t) * 16 + ocg * 4];
      const f32x2 w01 = w4.xy, w23 = w4.zw;
      #pragma unroll
      for (int r = 0; r < 4; ++r)
        #pragma unroll
        for (int c = 0; c < 4; ++c) {
          const int cc = c + kx;
          const f32x2 vp = wp[r + ky][cc >> 1];
          if (cc & 1) { pk_fma_hi(acc01[r * 4 + c], vp, w01); pk_fma_hi(acc23[r * 4 + c], vp, w23); }
          else        { pk_fma_lo(acc01[r * 4 + c], vp, w01); pk_fma_lo(acc23[r * 4 + c], vp, w23); }
        }
    }
  }
  #pragma unroll
  for (int pr = 0; pr < 2; ++pr) {
    const f32x2* ac = pr ? acc23 : acc01;
    const int oc0 = ocg * 4 + pr * 2;
    const float bx = b1[oc0], by = b1[oc0 + 1];
    #pragma unroll
    for (int pyi = 0; pyi < 2; ++pyi)
      #pragma unroll
      for (int pxi = 0; pxi < 2; ++pxi) {
        const int r0 = 2 * pyi, c0 = 2 * pxi;
        const f32x2 A = ac[r0 * 4 + c0], B = ac[r0 * 4 + c0 + 1];
        const f32x2 C = ac[(r0 + 1) * 4 + c0], D = ac[(r0 + 1) * 4 + c0 + 1];
        const float m0 = fmaxf(fmaxf(A.x, B.x), fmaxf(C.x, D.x));
        const float m1 = fmaxf(fmaxf(A.y, B.y), fmaxf(C.y, D.y));
        const int py = 2 * ty + pyi, px = 2 * tx + pxi;
        const int idx = ((b * 16 + oc0) << 8) + py * 16 + px;
        h1[idx]       = fmaxf(m0 + bx, 0.f);
        h1[idx + 256] = fmaxf(m1 + by, 0.f);
      }
  }
}

// ------------------------------------------------------------------- conv2
// h1 -> relu+pool -> h2[4096,32,8,8]. 2 images/block. stride 18 (bank-spread
// {0,8,16,24} across wave addresses -> 2-way, free). Rows read as 3x b64.
__global__ __launch_bounds__(256) void conv2_kernel(
    const float* __restrict__ h1, const float* __restrict__ w2t,
    const float* __restrict__ b2, float* __restrict__ h2) {
  __shared__ __align__(16) float s_in[2 * 16 * 18 * 18];  // 41.5 KB
  const int tid = threadIdx.x;
  const int b0 = blockIdx.x * 2;

  for (int i = tid; i < 10368; i += 256) s_in[i] = 0.f;
  __syncthreads();
  for (int i = tid; i < 8192; i += 256) {
    int img = i >> 12, rem = i & 4095;
    int c = rem >> 8, y = (rem >> 4) & 15, xx = rem & 15;
    s_in[img * 5184 + c * 324 + (y + 1) * 18 + (xx + 1)] = h1[(b0 + img) * 4096 + rem];
  }
  __syncthreads();

  const int ocg = tid & 7;
  const int tile = (tid >> 3) & 15;
  const int img = tid >> 7;
  const int ty = tile >> 2, tx = tile & 3;
  const int Y = 4 * ty, X = 4 * tx;
  const float* __restrict__ wbase = w2t + ocg * 4;

  f32x2 acc01[16], acc23[16];
  #pragma unroll
  for (int i = 0; i < 16; ++i) { acc01[i] = (f32x2)(0.f); acc23[i] = (f32x2)(0.f); }

  const int ibase0 = img * 5184 + Y * 18 + X;
  for (int ic = 0; ic < 16; ++ic) {
    f32x2 wp[6][3];
    const int base = ibase0 + ic * 324;
    #pragma unroll
    for (int r = 0; r < 6; ++r)
      #pragma unroll
      for (int j = 0; j < 3; ++j)
        wp[r][j] = *(const f32x2*)&s_in[base + r * 18 + 2 * j];
    const float* __restrict__ wc = wbase + ic * 288;
    #pragma unroll
    for (int t = 0; t < 9; ++t) {
      const int ky = t / 3, kx = t % 3;
      const f32x4 w4 = *(const f32x4*)&wc[t * 32];
      const f32x2 w01 = w4.xy, w23 = w4.zw;
      #pragma unroll
      for (int r = 0; r < 4; ++r)
        #pragma unroll
        for (int c = 0; c < 4; ++c) {
          const int cc = c + kx;
          const f32x2 vp = wp[r + ky][cc >> 1];
          if (cc & 1) { pk_fma_hi(acc01[r * 4 + c], vp, w01); pk_fma_hi(acc23[r * 4 + c], vp, w23); }
          else        { pk_fma_lo(acc01[r * 4 + c], vp, w01); pk_fma_lo(acc23[r * 4 + c], vp, w23); }
        }
    }
  }
  #pragma unroll
  for (int pr = 0; pr < 2; ++pr) {
    const f32x2* ac = pr ? acc23 : acc01;
    const int oc0 = ocg * 4 + pr * 2;
    const float bx = b2[oc0], by = b2[oc0 + 1];
    #pragma unroll
    for (int pyi = 0; pyi < 2; ++pyi)
      #pragma unroll
      for (int pxi = 0; pxi < 2; ++pxi) {
        const int r0 = 2 * pyi, c0 = 2 * pxi;
        const f32x2 A = ac[r0 * 4 + c0], B = ac[r0 * 4 + c0 + 1];
        const f32x2 C = ac[(r0 + 1) * 4 + c0], D = ac[(r0 + 1) * 4 + c0 + 1];
        const float m0 = fmaxf(fmaxf(A.x, B.x), fmaxf(C.x, D.x));
        const float m1 = fmaxf(fmaxf(A.y, B.y), fmaxf(C.y, D.y));
        const int py = 2 * ty + pyi, px = 2 * tx + pxi;
        const int idx = ((b0 + img) * 32 + oc0) * 64 + py * 8 + px;
        h2[idx]      = fmaxf(m0 + bx, 0.f);
        h2[idx + 64] = fmaxf(m1 + by, 0.f);
      }
  }
}

// ------------------------------------------------------------------- conv3
// h2 -> relu+pool -> h3[4096,64,4,4]. 4 images/block. stride 10 is already
// conflict-free (wave addrs at banks 0/4/8/12). Rows read as 3x b64.
__global__ __launch_bounds__(256) void conv3_kernel(
    const float* __restrict__ h2, const float* __restrict__ w3t,
    const float* __restrict__ b3, float* __restrict__ h3) {
  __shared__ __align__(16) float s_in[4 * 32 * 10 * 10];  // 51.2 KB
  const int tid = threadIdx.x;
  const int b0 = blockIdx.x * 4;

  for (int i = tid; i < 12800; i += 256) s_in[i] = 0.f;
  __syncthreads();
  for (int i = tid; i < 8192; i += 256) {
    int img = i >> 11, rem = i & 2047;
    int c = rem >> 6, y = (rem >> 3) & 7, xx = rem & 7;
    s_in[img * 3200 + c * 100 + (y + 1) * 10 + (xx + 1)] = h2[(b0 + img) * 2048 + rem];
  }
  __syncthreads();

  const int ocg = tid & 15;
  const int tile = (tid >> 4) & 3;
  const int img = tid >> 6;
  const int ty = tile >> 1, tx = tile & 1;
  const int Y = 4 * ty, X = 4 * tx;
  const float* __restrict__ wbase = w3t + ocg * 4;

  f32x2 acc01[16], acc23[16];
  #pragma unroll
  for (int i = 0; i < 16; ++i) { acc01[i] = (f32x2)(0.f); acc23[i] = (f32x2)(0.f); }

  const int ibase0 = img * 3200 + Y * 10 + X;
  for (int ic = 0; ic < 32; ++ic) {
    f32x2 wp[6][3];
    const int base = ibase0 + ic * 100;
    #pragma unroll
    for (int r = 0; r < 6; ++r)
      #pragma unroll
      for (int j = 0; j < 3; ++j)
        wp[r][j] = *(const f32x2*)&s_in[base + r * 10 + 2 * j];
    const float* __restrict__ wc = wbase + ic * 576;
    #pragma unroll
    for (int t = 0; t < 9; ++t) {
      const int ky = t / 3, kx = t % 3;
      const f32x4 w4 = *(const f32x4*)&wc[t * 64];
      const f32x2 w01 = w4.xy, w23 = w4.zw;
      #pragma unroll
      for (int r = 0; r < 4; ++r)
        #pragma unroll
        for (int c = 0; c < 4; ++c) {
          const int cc = c + kx;
          const f32x2 vp = wp[r + ky][cc >> 1];
          if (cc & 1) { pk_fma_hi(acc01[r * 4 + c], vp, w01); pk_fma_hi(acc23[r * 4 + c], vp, w23); }
          else        { pk_fma_lo(acc01[r * 4 + c], vp, w01); pk_fma_lo(acc23[r * 4 + c], vp, w23); }
        }
    }
  }
  #pragma unroll
  for (int pr = 0; pr < 2; ++pr) {
    const f32x2* ac = pr ? acc23 : acc01;
    const int oc0 = ocg * 4 + pr * 2;
    const float bx = b3[oc0], by = b3[oc0 + 1];
    #pragma unroll
    for (int pyi = 0; pyi < 2; ++pyi)
      #pragma unroll
      for (int pxi = 0; pxi < 2; ++pxi) {
        const int r0 = 2 * pyi, c0 = 2 * pxi;
        const f32x2 A = ac[r0 * 4 + c0], B = ac[r0 * 4 + c0 + 1];
        const f32x2 C = ac[(r0 + 1) * 4 + c0], D = ac[(r0 + 1) * 4 + c0 + 1];
        const float m0 = fmaxf(fmaxf(A.x, B.x), fmaxf(C.x, D.x));
        const float m1 = fmaxf(fmaxf(A.y, B.y), fmaxf(C.y, D.y));
        const int py = 2 * ty + pyi, px = 2 * tx + pxi;
        const int idx = ((b0 + img) * 64 + oc0) * 16 + py * 4 + px;
        h3[idx]      = fmaxf(m0 + bx, 0.f);
        h3[idx + 16] = fmaxf(m1 + by, 0.f);
      }
  }
}

// ---------------------------------------------------------------------- fc
__global__ __launch_bounds__(256) void fc_kernel(
    const float* __restrict__ h3, const float* __restrict__ fw,
    const float* __restrict__ fb, float* __restrict__ out) {
  const int tid = threadIdx.x;
  const int lane = tid & 63;
  const int b = blockIdx.x * 4 + (tid >> 6);
  float hv[16];
  #pragma unroll
  for (int i = 0; i < 16; ++i) hv[i] = h3[b * 1024 + i * 64 + lane];
  #pragma unroll
  for (int j = 0; j < 10; ++j) {
    float dot = 0.f;
    #pragma unroll
    for (int i = 0; i < 16; ++i)
      dot = fmaf(hv[i], fw[j * 1024 + i * 64 + lane], dot);
    #pragma unroll
    for (int s = 32; s > 0; s >>= 1) dot += __shfl_xor(dot, s, 64);
    if (lane == 0) out[b * 10 + j] = dot + fb[j];
  }
}

// -------------------------------------------------------------------- launch
extern "C" void kernel_launch(void* const* d_in, const int* in_sizes, int n_in,
                              void* d_out, int out_size, void* d_ws, size_t ws_size,
                              hipStream_t stream) {
  const float* x   = (const float*)d_in[0];
  const float* w1  = (const float*)d_in[1];
  const float* b1  = (const float*)d_in[2];
  const float* w2  = (const float*)d_in[3];
  const float* b2  = (const float*)d_in[4];
  const float* w3  = (const float*)d_in[5];
  const float* b3  = (const float*)d_in[6];
  const float* fcw = (const float*)d_in[7];
  const float* fcb = (const float*)d_in[8];
  float* ws  = (float*)d_ws;
  float* out = (float*)d_out;

  hipLaunchKernelGGL(transpose_weights, dim3(90), dim3(256), 0, stream, w2, w3, ws);
  hipLaunchKernelGGL(conv1_kernel, dim3(4096), dim3(256), 0, stream,
                     x, w1, b1, ws + H1_OFF);
  hipLaunchKernelGGL(conv2_kernel, dim3(2048), dim3(256), 0, stream,
                     ws + H1_OFF, ws + W2T_OFF, b2, ws + H2_OFF);
  hipLaunchKernelGGL(conv3_kernel, dim3(1024), dim3(256), 0, stream,
                     ws + H2_OFF, ws + W3T_OFF, b3, ws + H3_OFF);
  hipLaunchKernelGGL(fc_kernel, dim3(1024), dim3(256), 0, stream,
                     ws + H3_OFF, fcw, fcb, out);
}

// Round 4
// 216.838 us; speedup vs baseline: 1.8571x; 1.6154x over previous
//
#include <hip/hip_runtime.h>

typedef float f32x2 __attribute__((ext_vector_type(2)));
typedef float f32x4 __attribute__((ext_vector_type(4)));
typedef float f32x16v __attribute__((ext_vector_type(16)));
typedef __bf16 bf16x8 __attribute__((ext_vector_type(8)));

// Packed fp32 FMA helpers (conv1 only).
__device__ __forceinline__ void pk_fma_lo(f32x2 &acc, f32x2 vp, f32x2 w) {
  asm("v_pk_fma_f32 %0, %1, %2, %0 op_sel_hi:[0,1,1]"
      : "+v"(acc) : "v"(vp), "v"(w));
}
__device__ __forceinline__ void pk_fma_hi(f32x2 &acc, f32x2 vp, f32x2 w) {
  asm("v_pk_fma_f32 %0, %1, %2, %0 op_sel:[1,0,0] op_sel_hi:[1,1,1]"
      : "+v"(acc) : "v"(vp), "v"(w));
}

// Workspace layout (float-slot offsets; total 29383168 floats = 117.53 MB,
// identical footprint to previous rounds):
//   h1_hi bf16[16.78M] @ 0         h1_lo @ 8388608
//   h2_hi bf16[8.39M]  @ 16777216  h2_lo @ 20971520
//   h3    f32 [4.19M]  @ 25165824
//   b2p   bf16[9216]   @ 29360128  (18 frags x 1024B, 32x32x16 B-layout)
//   b3p   bf16[36864]  @ 29364736  (72 frags x 1024B, 16x16x32 B-layout)
#define H1HI_OFF 0u
#define H1LO_OFF 8388608u
#define H2HI_OFF 16777216u
#define H2LO_OFF 20971520u
#define H3_OFF   25165824u
#define B2P_OFF  29360128u
#define B3P_OFF  29364736u

// ------------------------------------------------------------- pack_weights
// b2p frag f = t*2+p (t=ky*3+kx, p=hi/lo): lane l, j: oc=l&31, ic=(l>>5)*8+j
// b3p frag f = t*8+nt*2+p: lane l, j: oc=nt*16+(l&15), ic=(l>>4)*8+j
__global__ __launch_bounds__(256) void pack_weights(
    const float* __restrict__ w2, const float* __restrict__ w3,
    __bf16* __restrict__ b2p, __bf16* __restrict__ b3p) {
  int i = blockIdx.x * 256 + threadIdx.x;
  if (i < 9216) {
    int f = i >> 9, r = i & 511;
    int l = r >> 3, j = r & 7;
    int t = f >> 1, p = f & 1;
    int ky = t / 3, kx = t % 3;
    int oc = l & 31, ic = ((l >> 5) << 3) + j;
    float v = w2[oc * 144 + ic * 9 + ky * 3 + kx];
    __bf16 hi = (__bf16)v;
    b2p[i] = p ? (__bf16)(v - (float)hi) : hi;
  } else if (i < 9216 + 36864) {
    int q = i - 9216;
    int f = q >> 9, r = q & 511;
    int l = r >> 3, j = r & 7;
    int t = f >> 3, nt = (f >> 1) & 3, p = f & 1;
    int ky = t / 3, kx = t % 3;
    int oc = nt * 16 + (l & 15), ic = ((l >> 4) << 3) + j;
    float v = w3[oc * 288 + ic * 9 + ky * 3 + kx];
    __bf16 hi = (__bf16)v;
    b3p[q] = p ? (__bf16)(v - (float)hi) : hi;
  }
}

// ------------------------------------------------------------------- conv1
// fp32 vector kernel (ic=3 is MFMA-hostile). Writes split channels-last h1:
// h1[img][y][x][ic=16] as hi/lo bf16.
__global__ __launch_bounds__(256) void conv1_kernel(
    const float* __restrict__ x, const float* __restrict__ w1,
    const float* __restrict__ b1,
    __bf16* __restrict__ h1h, __bf16* __restrict__ h1l) {
  __shared__ __align__(16) float s_in[3 * 34 * 34];
  __shared__ __align__(16) float s_w[27 * 16];
  const int tid = threadIdx.x;
  const int b = blockIdx.x;

  for (int i = tid; i < 3 * 34 * 34; i += 256) s_in[i] = 0.f;
  __syncthreads();
  for (int i = tid; i < 3 * 1024; i += 256) {
    int c = i >> 10, rem = i & 1023, y = rem >> 5, xx = rem & 31;
    s_in[c * 1156 + (y + 1) * 34 + (xx + 1)] = x[b * 3072 + i];
  }
  for (int i = tid; i < 432; i += 256) {
    int oc = i / 27, r = i % 27;
    s_w[r * 16 + oc] = w1[i];
  }
  __syncthreads();

  const int ocg = tid & 3;
  const int tile = tid >> 2;
  const int ty = tile >> 3, tx = tile & 7;
  const int Y = 4 * ty, X = 4 * tx;

  f32x2 acc01[16], acc23[16];
  #pragma unroll
  for (int i = 0; i < 16; ++i) { acc01[i] = (f32x2)(0.f); acc23[i] = (f32x2)(0.f); }

  #pragma unroll
  for (int ic = 0; ic < 3; ++ic) {
    f32x2 wp[6][3];
    const int base = ic * 1156 + Y * 34 + X;
    #pragma unroll
    for (int r = 0; r < 6; ++r)
      #pragma unroll
      for (int j = 0; j < 3; ++j) {
        wp[r][j].x = s_in[base + r * 34 + 2 * j];
        wp[r][j].y = s_in[base + r * 34 + 2 * j + 1];
      }
    #pragma unroll
    for (int t = 0; t < 9; ++t) {
      const int ky = t / 3, kx = t % 3;
      const f32x4 w4 = *(const f32x4*)&s_w[(ic * 9 + t) * 16 + ocg * 4];
      const f32x2 w01 = w4.xy, w23 = w4.zw;
      #pragma unroll
      for (int r = 0; r < 4; ++r)
        #pragma unroll
        for (int c = 0; c < 4; ++c) {
          const int cc = c + kx;
          const f32x2 vp = wp[r + ky][cc >> 1];
          if (cc & 1) { pk_fma_hi(acc01[r * 4 + c], vp, w01); pk_fma_hi(acc23[r * 4 + c], vp, w23); }
          else        { pk_fma_lo(acc01[r * 4 + c], vp, w01); pk_fma_lo(acc23[r * 4 + c], vp, w23); }
        }
    }
  }
  #pragma unroll
  for (int pr = 0; pr < 2; ++pr) {
    const f32x2* ac = pr ? acc23 : acc01;
    const int oc0 = ocg * 4 + pr * 2;
    const float bx = b1[oc0], by = b1[oc0 + 1];
    #pragma unroll
    for (int pyi = 0; pyi < 2; ++pyi)
      #pragma unroll
      for (int pxi = 0; pxi < 2; ++pxi) {
        const int r0 = 2 * pyi, c0 = 2 * pxi;
        const f32x2 A = ac[r0 * 4 + c0], B = ac[r0 * 4 + c0 + 1];
        const f32x2 C = ac[(r0 + 1) * 4 + c0], D = ac[(r0 + 1) * 4 + c0 + 1];
        const float m0 = fmaxf(fmaxf(A.x, B.x), fmaxf(C.x, D.x));
        const float m1 = fmaxf(fmaxf(A.y, B.y), fmaxf(C.y, D.y));
        const int py = 2 * ty + pyi, px = 2 * tx + pxi;
        const float v0 = fmaxf(m0 + bx, 0.f);
        const float v1 = fmaxf(m1 + by, 0.f);
        const int idx = (b * 256 + py * 16 + px) * 16 + oc0;
        __bf16 v0h = (__bf16)v0, v1h = (__bf16)v1;
        h1h[idx] = v0h;      h1h[idx + 1] = v1h;
        h1l[idx] = (__bf16)(v0 - (float)v0h);
        h1l[idx + 1] = (__bf16)(v1 - (float)v1h);
      }
  }
}

// ------------------------------------------------------------------- conv2
// MFMA 32x32x16 bf16, bf16x2 split (3 terms). 1 image/block.
// LDS image: [part][row 0..17][col 0..17][ic16], col stride 24 ush (48B),
// row stride 432 ush. Lane: m=lane&31 -> x=m&15, yoff=m>>4; kh=lane>>5.
__global__ __launch_bounds__(256) void conv2_kernel(
    const __bf16* __restrict__ h1h, const __bf16* __restrict__ h1l,
    const __bf16* __restrict__ b2p, const float* __restrict__ b2,
    __bf16* __restrict__ h2h, __bf16* __restrict__ h2l) {
  __shared__ __align__(16) unsigned short s2[2 * 7776];
  const int tid = threadIdx.x;
  const int img = blockIdx.x;

  for (int i = tid; i < 3888; i += 256) ((unsigned long long*)s2)[i] = 0ull;
  __syncthreads();
  for (int e = tid; e < 1024; e += 256) {
    int part = e >> 9, r = e & 511;
    int ic8 = (r & 1) * 8, xx = (r >> 1) & 15, y = r >> 5;
    const __bf16* src = (part ? h1l : h1h) + img * 4096 + (y * 16 + xx) * 16 + ic8;
    uint4 v = *(const uint4*)src;
    *(uint4*)&s2[part * 7776 + (y + 1) * 432 + (xx + 1) * 24 + ic8] = v;
  }
  const int lane = tid & 63;
  bf16x8 Bf[18];
  #pragma unroll
  for (int f = 0; f < 18; ++f)
    Bf[f] = *(const bf16x8*)(b2p + f * 512 + lane * 8);
  __syncthreads();

  const int wv = tid >> 6;
  const int xm = lane & 15, yoff = (lane >> 4) & 1, kh = lane >> 5;

  f32x16v acc0, acc1;
  #pragma unroll
  for (int r = 0; r < 16; ++r) { acc0[r] = 0.f; acc1[r] = 0.f; }

  #pragma unroll
  for (int t = 0; t < 9; ++t) {
    const int ky = t / 3, kx = t % 3;
    const int col = (xm + kx) * 24 + kh * 8;
    const int row0 = (4 * wv + yoff + ky) * 432 + col;   // Mtile0: y0=4wv
    const int row1 = row0 + 864;                          // Mtile1: y0=4wv+2
    bf16x8 a0h = *(const bf16x8*)&s2[row0];
    bf16x8 a0l = *(const bf16x8*)&s2[7776 + row0];
    bf16x8 a1h = *(const bf16x8*)&s2[row1];
    bf16x8 a1l = *(const bf16x8*)&s2[7776 + row1];
    acc0 = __builtin_amdgcn_mfma_f32_32x32x16_bf16(a0h, Bf[t * 2],     acc0, 0, 0, 0);
    acc1 = __builtin_amdgcn_mfma_f32_32x32x16_bf16(a1h, Bf[t * 2],     acc1, 0, 0, 0);
    acc0 = __builtin_amdgcn_mfma_f32_32x32x16_bf16(a0h, Bf[t * 2 + 1], acc0, 0, 0, 0);
    acc1 = __builtin_amdgcn_mfma_f32_32x32x16_bf16(a1h, Bf[t * 2 + 1], acc1, 0, 0, 0);
    acc0 = __builtin_amdgcn_mfma_f32_32x32x16_bf16(a0l, Bf[t * 2],     acc0, 0, 0, 0);
    acc1 = __builtin_amdgcn_mfma_f32_32x32x16_bf16(a1l, Bf[t * 2],     acc1, 0, 0, 0);
  }

  // Epilogue: C row m=(reg&3)+4*(lane>>5)+8*(reg>>2) -> x=m&15, yoff=m>>4.
  const int oc = lane & 31, hh = lane >> 5;
  const float bias = b2[oc];
  #pragma unroll
  for (int i2 = 0; i2 < 2; ++i2) {
    const f32x16v& a = i2 ? acc1 : acc0;
    const int py = 2 * wv + i2;
    #pragma unroll
    for (int bq = 0; bq < 2; ++bq)
      #pragma unroll
      for (int rq = 0; rq < 2; ++rq) {
        const int r0 = bq * 4 + rq * 2;
        float v = fmaxf(fmaxf(a[r0], a[r0 + 1]), fmaxf(a[r0 + 8], a[r0 + 9]));
        v = fmaxf(v + bias, 0.f);
        const int px = 2 * hh + 4 * bq + rq;
        const int idx = ((img * 8 + py) * 8 + px) * 32 + oc;
        __bf16 vh = (__bf16)v;
        h2h[idx] = vh;
        h2l[idx] = (__bf16)(v - (float)vh);
      }
  }
}

// ------------------------------------------------------------------- conv3
// MFMA 16x16x32 bf16, split 3-term. 4 images/block, wave=image.
// LDS: [img][part][row 0..9][col 0..9][ic32], col stride 40 ush (80B),
// row stride 400 ush. Lane: m=lane&15 -> x=m&7, yoff=m>>3; quad=lane>>4.
__global__ __launch_bounds__(256) void conv3_kernel(
    const __bf16* __restrict__ h2h, const __bf16* __restrict__ h2l,
    const __bf16* __restrict__ b3p, const float* __restrict__ b3,
    float* __restrict__ h3) {
  __shared__ __align__(16) unsigned short s3[8 * 4000];
  const int tid = threadIdx.x;
  const int b0 = blockIdx.x * 4;

  for (int i = tid; i < 8000; i += 256) ((unsigned long long*)s3)[i] = 0ull;
  __syncthreads();
  for (int e = tid; e < 2048; e += 256) {
    int im = e >> 9, part = (e >> 8) & 1, r = e & 255;
    int ic8 = (r & 3) * 8, xx = (r >> 2) & 7, y = r >> 5;
    const __bf16* src = (part ? h2l : h2h) + ((b0 + im) * 64 + y * 8 + xx) * 32 + ic8;
    uint4 v = *(const uint4*)src;
    *(uint4*)&s3[(im * 2 + part) * 4000 + (y + 1) * 400 + (xx + 1) * 40 + ic8] = v;
  }
  __syncthreads();

  const int lane = tid & 63;
  const int im = tid >> 6;
  const int m = lane & 15, quad = lane >> 4;
  const int xm = m & 7, yoff = m >> 3;
  const int baseh = im * 8000, basel = baseh + 4000;

  f32x4 acc[4][4];
  #pragma unroll
  for (int mt = 0; mt < 4; ++mt)
    #pragma unroll
    for (int nt = 0; nt < 4; ++nt)
      #pragma unroll
      for (int r = 0; r < 4; ++r) acc[mt][nt][r] = 0.f;

  #pragma unroll
  for (int t = 0; t < 9; ++t) {
    const int ky = t / 3, kx = t % 3;
    bf16x8 Bt[8];
    #pragma unroll
    for (int f = 0; f < 8; ++f)
      Bt[f] = *(const bf16x8*)(b3p + (t * 8 + f) * 512 + lane * 8);
    #pragma unroll
    for (int mt = 0; mt < 4; ++mt) {
      const int ro = (2 * mt + yoff + ky) * 400 + (xm + kx) * 40 + quad * 8;
      bf16x8 ah = *(const bf16x8*)&s3[baseh + ro];
      bf16x8 al = *(const bf16x8*)&s3[basel + ro];
      #pragma unroll
      for (int nt = 0; nt < 4; ++nt)
        acc[mt][nt] = __builtin_amdgcn_mfma_f32_16x16x32_bf16(ah, Bt[nt * 2],     acc[mt][nt], 0, 0, 0);
      #pragma unroll
      for (int nt = 0; nt < 4; ++nt)
        acc[mt][nt] = __builtin_amdgcn_mfma_f32_16x16x32_bf16(ah, Bt[nt * 2 + 1], acc[mt][nt], 0, 0, 0);
      #pragma unroll
      for (int nt = 0; nt < 4; ++nt)
        acc[mt][nt] = __builtin_amdgcn_mfma_f32_16x16x32_bf16(al, Bt[nt * 2],     acc[mt][nt], 0, 0, 0);
    }
  }

  // Epilogue: C row m=quad*4+reg -> x=(quad&1)*4+reg, yoff=quad>>1.
  // x-pairs = reg pairs (in-lane); y-pairs = lane^32 (shfl).
  const int ocl = lane & 15;
  #pragma unroll
  for (int mt = 0; mt < 4; ++mt)
    #pragma unroll
    for (int nt = 0; nt < 4; ++nt) {
      float p0 = fmaxf(acc[mt][nt][0], acc[mt][nt][1]);
      float p1 = fmaxf(acc[mt][nt][2], acc[mt][nt][3]);
      p0 = fmaxf(p0, __shfl_xor(p0, 32, 64));
      p1 = fmaxf(p1, __shfl_xor(p1, 32, 64));
      if (quad < 2) {
        const int oc = nt * 16 + ocl;
        const float bias = b3[oc];
        const float v0 = fmaxf(p0 + bias, 0.f);
        const float v1 = fmaxf(p1 + bias, 0.f);
        const int base = ((b0 + im) * 64 + oc) * 16 + mt * 4 + (quad & 1) * 2;
        h3[base] = v0;
        h3[base + 1] = v1;
      }
    }
}

// ---------------------------------------------------------------------- fc
__global__ __launch_bounds__(256) void fc_kernel(
    const float* __restrict__ h3, const float* __restrict__ fw,
    const float* __restrict__ fb, float* __restrict__ out) {
  const int tid = threadIdx.x;
  const int lane = tid & 63;
  const int b = blockIdx.x * 4 + (tid >> 6);
  float hv[16];
  #pragma unroll
  for (int i = 0; i < 16; ++i) hv[i] = h3[b * 1024 + i * 64 + lane];
  #pragma unroll
  for (int j = 0; j < 10; ++j) {
    float dot = 0.f;
    #pragma unroll
    for (int i = 0; i < 16; ++i)
      dot = fmaf(hv[i], fw[j * 1024 + i * 64 + lane], dot);
    #pragma unroll
    for (int s = 32; s > 0; s >>= 1) dot += __shfl_xor(dot, s, 64);
    if (lane == 0) out[b * 10 + j] = dot + fb[j];
  }
}

// -------------------------------------------------------------------- launch
extern "C" void kernel_launch(void* const* d_in, const int* in_sizes, int n_in,
                              void* d_out, int out_size, void* d_ws, size_t ws_size,
                              hipStream_t stream) {
  const float* x   = (const float*)d_in[0];
  const float* w1  = (const float*)d_in[1];
  const float* b1  = (const float*)d_in[2];
  const float* w2  = (const float*)d_in[3];
  const float* b2  = (const float*)d_in[4];
  const float* w3  = (const float*)d_in[5];
  const float* b3  = (const float*)d_in[6];
  const float* fcw = (const float*)d_in[7];
  const float* fcb = (const float*)d_in[8];
  float* ws  = (float*)d_ws;
  float* out = (float*)d_out;

  __bf16* h1h = (__bf16*)(ws + H1HI_OFF);
  __bf16* h1l = (__bf16*)(ws + H1LO_OFF);
  __bf16* h2h = (__bf16*)(ws + H2HI_OFF);
  __bf16* h2l = (__bf16*)(ws + H2LO_OFF);
  float*  h3  = ws + H3_OFF;
  __bf16* b2p = (__bf16*)(ws + B2P_OFF);
  __bf16* b3p = (__bf16*)(ws + B3P_OFF);

  hipLaunchKernelGGL(pack_weights, dim3(180), dim3(256), 0, stream, w2, w3, b2p, b3p);
  hipLaunchKernelGGL(conv1_kernel, dim3(4096), dim3(256), 0, stream, x, w1, b1, h1h, h1l);
  hipLaunchKernelGGL(conv2_kernel, dim3(4096), dim3(256), 0, stream, h1h, h1l, b2p, b2, h2h, h2l);
  hipLaunchKernelGGL(conv3_kernel, dim3(1024), dim3(256), 0, stream, h2h, h2l, b3p, b3, h3);
  hipLaunchKernelGGL(fc_kernel, dim3(1024), dim3(256), 0, stream, h3, fcw, fcb, out);
}